// Round 10
// baseline (2148.072 us; speedup 1.0000x reference)
//
#include <hip/hip_runtime.h>

typedef float v16f __attribute__((ext_vector_type(16)));
typedef float v4f __attribute__((ext_vector_type(4)));
typedef _Float16 v8h __attribute__((ext_vector_type(8)));

#define NROWS 131072
#define DIM 128
#define NCB 4
#define CBS 2048
#define ZQ_SIZE ((size_t)NROWS * DIM)
#define CODES_SIZE ((size_t)NROWS * NCB)
#define CHUNK_BYTES 16384
#define CBQ_TOTAL ((size_t)NCB * 64 * CHUNK_BYTES)  /* 4 MiB */
#define INV4096 2.44140625e-4f

#define MFMA16(a, b, c) __builtin_amdgcn_mfma_f32_32x32x16_f16((a), (b), (c), 0, 0, 0)

// Tile codebook into per-chunk f16 2-limb image (identical to rounds 3/6/8).
__global__ void prep_cb(const float* __restrict__ cb, _Float16* __restrict__ cbq) {
    const int g = blockIdx.x * 256 + threadIdx.x;   // 65536 threads
    const int c   = g & 7;
    const int col = (g >> 3) & 31;
    const int q   = (g >> 8) & 63;
    const int s   = g >> 14;
    const float* src = cb + (size_t)(s * CBS + q * 32 + col) * DIM + 16 * c;
    _Float16* base = cbq + (size_t)(s * 64 + q) * 8192;  // f16 elems
#pragma unroll
    for (int hh = 0; hh < 2; ++hh) {
        v8h p0, p1;
#pragma unroll
        for (int j = 0; j < 8; ++j) {
            const float v = src[8 * hh + j];
            const _Float16 h0 = (_Float16)v;
            const float t = v - (float)h0;        // exact
            p0[j] = h0;
            p1[j] = (_Float16)(t * 4096.0f);      // scaled limb: normal range
        }
        *reinterpret_cast<v8h*>(base + (size_t)c * 512 + (hh * 32 + col) * 8) = p0;
        *reinterpret_cast<v8h*>(base + (size_t)(8 + c) * 512 + (hh * 32 + col) * 8) = p1;
    }
}

// full code norms ||c||^2 (ref-identical usage)
__global__ void prep_cn(const float* __restrict__ cb, float* __restrict__ cn) {
    const int g = blockIdx.x * 256 + threadIdx.x;   // 8192 threads
    const float* src = cb + (size_t)g * DIM;
    float acc = 0.0f;
    for (int i = 0; i < 32; ++i) {
        const v4f v = *reinterpret_cast<const v4f*>(src + 4 * i);
        acc = fmaf(v.x, v.x, acc); acc = fmaf(v.y, v.y, acc);
        acc = fmaf(v.z, v.z, acc); acc = fmaf(v.w, v.w, acc);
    }
    cn[g] = acc;
}

// Exact 3-limb split of f32: v == h0 + h1*2^-12 + h2*2^-24 (bit-exact).
__device__ __forceinline__ void split3(float v, _Float16* h0, _Float16* h1, _Float16* h2) {
    const _Float16 a = (_Float16)v;
    const float t1 = v - (float)a;           // exact
    const float s1 = t1 * 4096.0f;           // exact (pow2)
    const _Float16 b = (_Float16)s1;
    const float s2 = (s1 - (float)b) * 4096.0f;  // exact
    *h0 = a; *h1 = b; *h2 = (_Float16)s2;    // last cast exact
}

__global__ __launch_bounds__(256, 2)
void rvq_main(const float* __restrict__ ze, const float* __restrict__ cbf,
              const _Float16* __restrict__ cbq, const float* __restrict__ cn,
              float* __restrict__ out)
{
    __shared__ __align__(16) char BB[2][CHUNK_BYTES];
    __shared__ __align__(16) float XNs[4][64];
    __shared__ int BIs[4][64];

    const int tid  = threadIdx.x;
    const int wid  = tid >> 6;
    const int lane = tid & 63;
    const int col  = lane & 31;
    const int h    = lane >> 5;
    const int rowstart = blockIdx.x * 256 + wid * 64;   // wave owns 64 rows (2 groups of 32)
    const int q0 = blockIdx.x & 63;                     // per-block sweep rotation

    // a2 (3rd limb) scratch: this block's own (not-yet-written) z_q output slab
    _Float16* a2 = (_Float16*)out + (size_t)blockIdx.x * 65536;

    v8h A0[2][8], A1[2][8];
    int mylast0 = 0, mylast1 = 0;

#pragma unroll 1
    for (int s = 0; s < NCB; ++s) {
        const char* cbq_s = (const char*)cbq + (size_t)(s * 64) * CHUNK_BYTES;

        // ---- issue chunk-q0 staging early (latency hidden under rebuild) ----
#pragma unroll
        for (int i = 0; i < 4; ++i) {
            const int blk = i * 4 + wid;
            __builtin_amdgcn_global_load_lds(
                (const __attribute__((address_space(1))) void*)(cbq_s + (size_t)q0 * CHUNK_BYTES + blk * 1024 + lane * 16),
                (__attribute__((address_space(3))) void*)(&BB[0][blk * 1024]), 16, 0, 0);
        }

        // ---- build/update residual limbs for both row-groups; x_norm -> LDS ----
#pragma unroll
        for (int g = 0; g < 2; ++g) {
            const int ml = g ? mylast1 : mylast0;
            const float* zr = ze + (size_t)(rowstart + g * 32 + col) * DIM + 8 * h;
            const float* qr = cbf + ((size_t)((s - 1) * CBS) + ml) * DIM + 8 * h;
            float pc[8];
#pragma unroll
            for (int c = 0; c < 8; ++c) {
                v8h a2v;
                float p[8];
                if (s == 0) {
                    const v4f v0 = __builtin_nontemporal_load(reinterpret_cast<const v4f*>(zr + 16 * c));
                    const v4f v1 = __builtin_nontemporal_load(reinterpret_cast<const v4f*>(zr + 16 * c + 4));
                    const float v[8] = {v0.x, v0.y, v0.z, v0.w, v1.x, v1.y, v1.z, v1.w};
#pragma unroll
                    for (int j = 0; j < 8; ++j) {
                        p[j] = v[j] * v[j];
                        _Float16 x0, x1, x2;
                        split3(v[j], &x0, &x1, &x2);
                        A0[g][c][j] = x0; A1[g][c][j] = x1; a2v[j] = x2;
                    }
                } else {
                    const v8h a2o = __builtin_nontemporal_load(
                        reinterpret_cast<const v8h*>(a2 + ((size_t)(g * 8 + c) * 256 + tid) * 8));
                    const v4f q0v = *reinterpret_cast<const v4f*>(qr + 16 * c);
                    const v4f q1v = *reinterpret_cast<const v4f*>(qr + 16 * c + 4);
                    const float qv[8] = {q0v.x, q0v.y, q0v.z, q0v.w, q1v.x, q1v.y, q1v.z, q1v.w};
#pragma unroll
                    for (int j = 0; j < 8; ++j) {
                        const float vr = fmaf((float)a2o[j], 0x1p-24f,
                                         fmaf((float)A1[g][c][j], 0x1p-12f, (float)A0[g][c][j]));
                        const float v = vr - qv[j];
                        p[j] = v * v;
                        _Float16 x0, x1, x2;
                        split3(v, &x0, &x1, &x2);
                        A0[g][c][j] = x0; A1[g][c][j] = x1; a2v[j] = x2;
                    }
                }
                __builtin_nontemporal_store(a2v,
                    reinterpret_cast<v8h*>(a2 + ((size_t)(g * 8 + c) * 256 + tid) * 8));
                pc[c] = ((p[0] + p[1]) + (p[2] + p[3])) + ((p[4] + p[5]) + (p[6] + p[7]));
            }
            const float xnp = ((pc[0] + pc[1]) + (pc[2] + pc[3])) + ((pc[4] + pc[5]) + (pc[6] + pc[7]));
            const float xn_own = xnp + __shfl_xor(xnp, 32);
            if (h == 0) XNs[wid][g * 32 + col] = xn_own;
        }
        __syncthreads();   // BB[0] landed + XNs visible

        float bestd0[16], bestd1[16];
        unsigned bq0[4] = {0u, 0u, 0u, 0u}, bq1[4] = {0u, 0u, 0u, 0u};
#pragma unroll
        for (int r = 0; r < 16; ++r) { bestd0[r] = INFINITY; bestd1[r] = INFINITY; }

#pragma unroll 1
        for (int q = 0; q < 64; ++q) {
            const int cur = q & 1;
            const int qc = (q0 + q) & 63;                  // rotated chunk index
            const float cnv = cn[s * CBS + qc * 32 + col];
            if (q < 63) {  // prefetch next (rotated) chunk into other buffer
                const int qn = (q0 + q + 1) & 63;
                const char* gq = cbq_s + (size_t)qn * CHUNK_BYTES;
#pragma unroll
                for (int i = 0; i < 4; ++i) {
                    const int blk = i * 4 + wid;
                    __builtin_amdgcn_global_load_lds(
                        (const __attribute__((address_space(1))) void*)(gq + blk * 1024 + lane * 16),
                        (__attribute__((address_space(3))) void*)(&BB[cur ^ 1][blk * 1024]), 16, 0, 0);
                }
            }
            const char* bb = &BB[cur][0];
            v16f aM0, aC0, aM1, aC1;
            __builtin_amdgcn_s_setprio(1);
            {
                const v8h b0 = *reinterpret_cast<const v8h*>(bb + lane * 16);
                const v8h b1 = *reinterpret_cast<const v8h*>(bb + 8 * 1024 + lane * 16);
                const v16f Z = {0.f,0.f,0.f,0.f,0.f,0.f,0.f,0.f,0.f,0.f,0.f,0.f,0.f,0.f,0.f,0.f};
                aM0 = MFMA16(A0[0][0], b0, Z);
                aC0 = MFMA16(A1[0][0], b0, Z);
                aM1 = MFMA16(A0[1][0], b0, Z);
                aC1 = MFMA16(A1[1][0], b0, Z);
                aC0 = MFMA16(A0[0][0], b1, aC0);
                aC1 = MFMA16(A0[1][0], b1, aC1);
            }
#pragma unroll
            for (int c = 1; c < 8; ++c) {
                const v8h b0 = *reinterpret_cast<const v8h*>(bb + (size_t)c * 1024 + lane * 16);
                const v8h b1 = *reinterpret_cast<const v8h*>(bb + (size_t)(8 + c) * 1024 + lane * 16);
                aM0 = MFMA16(A0[0][c], b0, aM0);
                aC0 = MFMA16(A1[0][c], b0, aC0);
                aM1 = MFMA16(A0[1][c], b0, aM1);
                aC1 = MFMA16(A1[1][c], b0, aC1);
                aC0 = MFMA16(A0[0][c], b1, aC0);
                aC1 = MFMA16(A0[1][c], b1, aC1);
            }
            __builtin_amdgcn_s_setprio(0);

            // ---- select: ref-identical d = (xn - 2*dot) + cn; (d,q) lexicographic ----
#pragma unroll
            for (int p = 0; p < 4; ++p) {
                const v4f xq = *reinterpret_cast<const v4f*>(&XNs[wid][8 * p + 4 * h]);
#pragma unroll
                for (int j = 0; j < 4; ++j) {
                    const int r = 4 * p + j;
                    const int sh = j * 8;
                    const float dotf = fmaf(aC0[r], INV4096, aM0[r]);
                    const float d = fmaf(-2.0f, dotf, xq[j]) + cnv;
                    const unsigned oq = (bq0[p] >> sh) & 255u;
                    const bool take = (d < bestd0[r]) ||
                                      ((d == bestd0[r]) && ((unsigned)qc < oq));
                    bestd0[r] = take ? d : bestd0[r];
                    const unsigned nb = (bq0[p] & ~(255u << sh)) | ((unsigned)qc << sh);
                    bq0[p] = take ? nb : bq0[p];
                }
            }
#pragma unroll
            for (int p = 0; p < 4; ++p) {
                const v4f xq = *reinterpret_cast<const v4f*>(&XNs[wid][32 + 8 * p + 4 * h]);
#pragma unroll
                for (int j = 0; j < 4; ++j) {
                    const int r = 4 * p + j;
                    const int sh = j * 8;
                    const float dotf = fmaf(aC1[r], INV4096, aM1[r]);
                    const float d = fmaf(-2.0f, dotf, xq[j]) + cnv;
                    const unsigned oq = (bq1[p] >> sh) & 255u;
                    const bool take = (d < bestd1[r]) ||
                                      ((d == bestd1[r]) && ((unsigned)qc < oq));
                    bestd1[r] = take ? d : bestd1[r];
                    const unsigned nb = (bq1[p] & ~(255u << sh)) | ((unsigned)qc << sh);
                    bq1[p] = take ? nb : bq1[p];
                }
            }
            __syncthreads();
        }

        // ---- cross-lane argmin per row (ties -> lower index); write codes ----
#pragma unroll
        for (int g = 0; g < 2; ++g) {
#pragma unroll
            for (int r = 0; r < 16; ++r) {
                float d = g ? bestd1[r] : bestd0[r];
                const unsigned bw = g ? bq1[r >> 2] : bq0[r >> 2];
                int bi = (int)((bw >> ((r & 3) * 8)) & 255u) * 32 + col;
#pragma unroll
                for (int m = 1; m <= 16; m <<= 1) {
                    const float od = __shfl_xor(d, m);
                    const int   oi = __shfl_xor(bi, m);
                    const bool take = (od < d) || ((od == d) && (oi < bi));
                    d  = take ? od : d;
                    bi = take ? oi : bi;
                }
                if (col == 0) {
                    const int row16 = (r & 3) + 8 * (r >> 2) + 4 * h;
                    BIs[wid][g * 32 + row16] = bi;
                    __builtin_nontemporal_store((float)bi,
                        &out[ZQ_SIZE + (size_t)(rowstart + g * 32 + row16) * NCB + s]);
                }
            }
        }
        __syncthreads();
        mylast0 = BIs[wid][col];
        mylast1 = BIs[wid][32 + col];
    }

    // ---- epilogue: reconstruct, subtract stage-3 code, z_q & loss ----
    v8h a2r[2][8];
#pragma unroll
    for (int g = 0; g < 2; ++g)
#pragma unroll
        for (int c = 0; c < 8; ++c)
            a2r[g][c] = __builtin_nontemporal_load(
                reinterpret_cast<const v8h*>(a2 + ((size_t)(g * 8 + c) * 256 + tid) * 8));
    __syncthreads();   // all a2 reads landed before z_q overwrites the slab

    float lsum = 0.0f;
#pragma unroll
    for (int g = 0; g < 2; ++g) {
        const int ml = g ? mylast1 : mylast0;
        const float* qr = cbf + ((size_t)(3 * CBS) + ml) * DIM + 8 * h;
        const float* zr = ze + (size_t)(rowstart + g * 32 + col) * DIM + 8 * h;
        float* orow = out + (size_t)(rowstart + g * 32 + col) * DIM + 8 * h;
#pragma unroll
        for (int c = 0; c < 8; ++c) {
            const v4f q0v = *reinterpret_cast<const v4f*>(qr + 16 * c);
            const v4f q1v = *reinterpret_cast<const v4f*>(qr + 16 * c + 4);
            const v4f z0 = __builtin_nontemporal_load(reinterpret_cast<const v4f*>(zr + 16 * c));
            const v4f z1 = __builtin_nontemporal_load(reinterpret_cast<const v4f*>(zr + 16 * c + 4));
            const float qv[8] = {q0v.x, q0v.y, q0v.z, q0v.w, q1v.x, q1v.y, q1v.z, q1v.w};
            const float zv[8] = {z0.x, z0.y, z0.z, z0.w, z1.x, z1.y, z1.z, z1.w};
            float o[8];
#pragma unroll
            for (int j = 0; j < 8; ++j) {
                const float vr = fmaf((float)a2r[g][c][j], 0x1p-24f,
                                 fmaf((float)A1[g][c][j], 0x1p-12f, (float)A0[g][c][j]));
                const float v = vr - qv[j];      // final residual (ref-identical chain)
                o[j] = zv[j] - v;                // z_q
                lsum = fmaf(v, v, lsum);
            }
            const v4f o0 = {o[0], o[1], o[2], o[3]};
            const v4f o1 = {o[4], o[5], o[6], o[7]};
            __builtin_nontemporal_store(o0, reinterpret_cast<v4f*>(orow + 16 * c));
            __builtin_nontemporal_store(o1, reinterpret_cast<v4f*>(orow + 16 * c + 4));
        }
    }
#pragma unroll
    for (int m = 1; m < 64; m <<= 1) lsum += __shfl_xor(lsum, m);
    if (lane == 0)
        atomicAdd(out + ZQ_SIZE + CODES_SIZE, lsum * (1.25f / 16777216.0f));
}

extern "C" void kernel_launch(void* const* d_in, const int* in_sizes, int n_in,
                              void* d_out, int out_size, void* d_ws, size_t ws_size,
                              hipStream_t stream)
{
    const float* ze  = (const float*)d_in[0];
    const float* cbf = (const float*)d_in[1];
    float* out = (float*)d_out;

    _Float16* cbq = (_Float16*)d_ws;
    float* cnall = (float*)((char*)d_ws + CBQ_TOTAL);

    (void)hipMemsetAsync(out + ZQ_SIZE + CODES_SIZE, 0, sizeof(float), stream);

    prep_cb<<<256, 256, 0, stream>>>(cbf, cbq);
    prep_cn<<<32, 256, 0, stream>>>(cbf, cnall);
    rvq_main<<<NROWS / 256, 256, 0, stream>>>(ze, cbf, cbq, cnall, out);
}

// Round 11
// 879.246 us; speedup vs baseline: 2.4431x; 2.4431x over previous
//
#include <hip/hip_runtime.h>

typedef float v16f __attribute__((ext_vector_type(16)));
typedef float v4f __attribute__((ext_vector_type(4)));
typedef _Float16 v8h __attribute__((ext_vector_type(8)));

#define NROWS 131072
#define DIM 128
#define NCB 4
#define CBS 2048
#define ZQ_SIZE ((size_t)NROWS * DIM)
#define CODES_SIZE ((size_t)NROWS * NCB)
#define CHUNK_BYTES 16384
#define PERIOD_BYTES 32768
#define CBQ_TOTAL ((size_t)NCB * 64 * CHUNK_BYTES)  /* 4 MiB */
#define INV4096 2.44140625e-4f

#define MFMA16(a, b, c) __builtin_amdgcn_mfma_f32_32x32x16_f16((a), (b), (c), 0, 0, 0)

// Tile codebook into per-chunk f16 2-limb image (identical to rounds 3/6/8).
__global__ void prep_cb(const float* __restrict__ cb, _Float16* __restrict__ cbq) {
    const int g = blockIdx.x * 256 + threadIdx.x;   // 65536 threads
    const int c   = g & 7;
    const int col = (g >> 3) & 31;
    const int q   = (g >> 8) & 63;
    const int s   = g >> 14;
    const float* src = cb + (size_t)(s * CBS + q * 32 + col) * DIM + 16 * c;
    _Float16* base = cbq + (size_t)(s * 64 + q) * 8192;  // f16 elems
#pragma unroll
    for (int hh = 0; hh < 2; ++hh) {
        v8h p0, p1;
#pragma unroll
        for (int j = 0; j < 8; ++j) {
            const float v = src[8 * hh + j];
            const _Float16 h0 = (_Float16)v;
            const float t = v - (float)h0;        // exact
            p0[j] = h0;
            p1[j] = (_Float16)(t * 4096.0f);      // scaled limb: normal range
        }
        *reinterpret_cast<v8h*>(base + (size_t)c * 512 + (hh * 32 + col) * 8) = p0;
        *reinterpret_cast<v8h*>(base + (size_t)(8 + c) * 512 + (hh * 32 + col) * 8) = p1;
    }
}

// full code norms ||c||^2 (ref-identical usage)
__global__ void prep_cn(const float* __restrict__ cb, float* __restrict__ cn) {
    const int g = blockIdx.x * 256 + threadIdx.x;   // 8192 threads
    const float* src = cb + (size_t)g * DIM;
    float acc = 0.0f;
    for (int i = 0; i < 32; ++i) {
        const v4f v = *reinterpret_cast<const v4f*>(src + 4 * i);
        acc = fmaf(v.x, v.x, acc); acc = fmaf(v.y, v.y, acc);
        acc = fmaf(v.z, v.z, acc); acc = fmaf(v.w, v.w, acc);
    }
    cn[g] = acc;
}

__global__ __launch_bounds__(256, 2)
void rvq_main(const float* __restrict__ ze, const float* __restrict__ cbf,
              const _Float16* __restrict__ cbq, const float* __restrict__ cn,
              float* __restrict__ out)
{
    __shared__ __align__(16) char BB[2][PERIOD_BYTES];   // 64 KB: two 2-chunk periods
    __shared__ int BIs[4][32];

    const int tid  = threadIdx.x;
    const int wid  = tid >> 6;
    const int lane = tid & 63;
    const int col  = lane & 31;
    const int h    = lane >> 5;
    const int rowbase = blockIdx.x * 128 + wid * 32;
    const int myrow   = rowbase + col;

    const float* zrow = ze + (size_t)myrow * DIM + 8 * h;

    // residual in registers: res[c][j] = r[myrow][16c + 8h + j]  (exact f32 chain)
    float res[8][8];
#pragma unroll
    for (int c = 0; c < 8; ++c) {
#pragma unroll
        for (int w2 = 0; w2 < 2; ++w2) {
            const v4f v = *reinterpret_cast<const v4f*>(zrow + 16 * c + 4 * w2);
            res[c][4 * w2 + 0] = v.x; res[c][4 * w2 + 1] = v.y;
            res[c][4 * w2 + 2] = v.z; res[c][4 * w2 + 3] = v.w;
        }
    }

#pragma unroll 1
    for (int s = 0; s < NCB; ++s) {
        const char* cbq_s = (const char*)cbq + (size_t)(s * 64) * CHUNK_BYTES;

        // ---- stage period 0 early (latency hidden under quantize) ----
#pragma unroll
        for (int u = 0; u < 8; ++u) {
            const int off = (u * 4 + wid) * 1024 + lane * 16;
            __builtin_amdgcn_global_load_lds(
                (const __attribute__((address_space(1))) void*)(cbq_s + off),
                (__attribute__((address_space(3))) void*)(&BB[0][off]), 16, 0, 0);
        }

        // ---- quantize residual to f16 2-limb fragments; x_norm ----
        v8h A0[8], A1[8];
        float pc[8];
#pragma unroll
        for (int c = 0; c < 8; ++c) {
            float p[8];
#pragma unroll
            for (int j = 0; j < 8; ++j) {
                const float v = res[c][j];
                p[j] = v * v;
                const _Float16 h0 = (_Float16)v;
                const float t = v - (float)h0;    // exact
                A0[c][j] = h0;
                A1[c][j] = (_Float16)(t * 4096.0f);
            }
            pc[c] = ((p[0] + p[1]) + (p[2] + p[3])) + ((p[4] + p[5]) + (p[6] + p[7]));
        }
        const float xnp = ((pc[0] + pc[1]) + (pc[2] + pc[3])) + ((pc[4] + pc[5]) + (pc[6] + pc[7]));
        const float xn_own = xnp + __shfl_xor(xnp, 32);
        float xns[16];
#pragma unroll
        for (int r = 0; r < 16; ++r)
            xns[r] = __shfl(xn_own, (r & 3) + 8 * (r >> 2) + 4 * h);

        float bestd[16];
        unsigned bq[4] = {0u, 0u, 0u, 0u};
#pragma unroll
        for (int r = 0; r < 16; ++r) bestd[r] = INFINITY;

        __syncthreads();   // period 0 landed

#pragma unroll 1
        for (int p = 0; p < 32; ++p) {
            const int cur = p & 1;
            const float cnv0 = cn[s * CBS + (2 * p) * 32 + col];
            const float cnv1 = cn[s * CBS + (2 * p + 1) * 32 + col];
            if (p < 31) {  // prefetch next period into other buffer
                const char* gp = cbq_s + (size_t)(p + 1) * PERIOD_BYTES;
#pragma unroll
                for (int u = 0; u < 8; ++u) {
                    const int off = (u * 4 + wid) * 1024 + lane * 16;
                    __builtin_amdgcn_global_load_lds(
                        (const __attribute__((address_space(1))) void*)(gp + off),
                        (__attribute__((address_space(3))) void*)(&BB[cur ^ 1][off]), 16, 0, 0);
                }
            }
#pragma unroll
            for (int sc = 0; sc < 2; ++sc) {
                const char* bb = &BB[cur][sc * CHUNK_BYTES];
                const float cnv = sc ? cnv1 : cnv0;
                const unsigned qg = (unsigned)(2 * p + sc);
                v16f aM, aC;
                __builtin_amdgcn_s_setprio(1);
                {
                    const v8h b0 = *reinterpret_cast<const v8h*>(bb + lane * 16);
                    const v8h b1 = *reinterpret_cast<const v8h*>(bb + 8 * 1024 + lane * 16);
                    const v16f Z = {0.f,0.f,0.f,0.f,0.f,0.f,0.f,0.f,0.f,0.f,0.f,0.f,0.f,0.f,0.f,0.f};
                    aM = MFMA16(A0[0], b0, Z);
                    aC = MFMA16(A1[0], b0, Z);
                    aC = MFMA16(A0[0], b1, aC);
                }
#pragma unroll
                for (int c = 1; c < 8; ++c) {
                    const v8h b0 = *reinterpret_cast<const v8h*>(bb + (size_t)c * 1024 + lane * 16);
                    const v8h b1 = *reinterpret_cast<const v8h*>(bb + (size_t)(8 + c) * 1024 + lane * 16);
                    aM = MFMA16(A0[c], b0, aM);
                    aC = MFMA16(A1[c], b0, aC);
                    aC = MFMA16(A0[c], b1, aC);
                }
                __builtin_amdgcn_s_setprio(0);
                // ---- select: ref-identical d = (xn - 2*dot) + cn; ascending q -> strict < ----
#pragma unroll
                for (int r = 0; r < 16; ++r) {
                    const int w = r >> 2, sh = (r & 3) * 8;
                    const float dotf = fmaf(aC[r], INV4096, aM[r]);
                    const float d = fmaf(-2.0f, dotf, xns[r]) + cnv;
                    const bool take = d < bestd[r];
                    bestd[r] = take ? d : bestd[r];
                    const unsigned nb = (bq[w] & ~(255u << sh)) | (qg << sh);
                    bq[w] = take ? nb : bq[w];
                }
            }
            __syncthreads();
        }

        // ---- cross-lane argmin per row (ties -> lower index); write codes ----
#pragma unroll
        for (int r = 0; r < 16; ++r) {
            float d = bestd[r];
            int bi = (int)((bq[r >> 2] >> ((r & 3) * 8)) & 255u) * 32 + col;
#pragma unroll
            for (int m = 1; m <= 16; m <<= 1) {
                const float od = __shfl_xor(d, m);
                const int   oi = __shfl_xor(bi, m);
                const bool take = (od < d) || ((od == d) && (oi < bi));
                d  = take ? od : d;
                bi = take ? oi : bi;
            }
            if (col == 0) {
                const int row16 = (r & 3) + 8 * (r >> 2) + 4 * h;
                BIs[wid][row16] = bi;
                out[ZQ_SIZE + (size_t)(rowbase + row16) * NCB + s] = (float)bi;
            }
        }
        __syncthreads();
        const int mybest = BIs[wid][col];

        // ---- residual -= chosen code (exact f32, original codebook) ----
        const float* qrow = cbf + ((size_t)(s * CBS) + mybest) * DIM + 8 * h;
#pragma unroll
        for (int c = 0; c < 8; ++c) {
#pragma unroll
            for (int w2 = 0; w2 < 2; ++w2) {
                const v4f v = *reinterpret_cast<const v4f*>(qrow + 16 * c + 4 * w2);
                res[c][4 * w2 + 0] -= v.x; res[c][4 * w2 + 1] -= v.y;
                res[c][4 * w2 + 2] -= v.z; res[c][4 * w2 + 3] -= v.w;
            }
        }
    }

    // ---- epilogue: z_q = z_e - r_final, loss = 1.25*mean(r^2) ----
    float lsum = 0.0f;
#pragma unroll
    for (int c = 0; c < 8; ++c) {
#pragma unroll
        for (int w2 = 0; w2 < 2; ++w2) {
            const v4f z = *reinterpret_cast<const v4f*>(zrow + 16 * c + 4 * w2);
            const float r0 = res[c][4 * w2 + 0], r1 = res[c][4 * w2 + 1];
            const float r2 = res[c][4 * w2 + 2], r3 = res[c][4 * w2 + 3];
            v4f o;
            o.x = z.x - r0; o.y = z.y - r1; o.z = z.z - r2; o.w = z.w - r3;
            *reinterpret_cast<v4f*>(out + (size_t)myrow * DIM + 16 * c + 8 * h + 4 * w2) = o;
            lsum = fmaf(r0, r0, lsum); lsum = fmaf(r1, r1, lsum);
            lsum = fmaf(r2, r2, lsum); lsum = fmaf(r3, r3, lsum);
        }
    }
#pragma unroll
    for (int m = 1; m < 64; m <<= 1) lsum += __shfl_xor(lsum, m);
    if (lane == 0)
        atomicAdd(out + ZQ_SIZE + CODES_SIZE, lsum * (1.25f / 16777216.0f));
}

extern "C" void kernel_launch(void* const* d_in, const int* in_sizes, int n_in,
                              void* d_out, int out_size, void* d_ws, size_t ws_size,
                              hipStream_t stream)
{
    const float* ze  = (const float*)d_in[0];
    const float* cbf = (const float*)d_in[1];
    float* out = (float*)d_out;

    _Float16* cbq = (_Float16*)d_ws;
    float* cnall = (float*)((char*)d_ws + CBQ_TOTAL);

    (void)hipMemsetAsync(out + ZQ_SIZE + CODES_SIZE, 0, sizeof(float), stream);

    prep_cb<<<256, 256, 0, stream>>>(cbf, cbq);
    prep_cn<<<32, 256, 0, stream>>>(cbf, cnall);
    rvq_main<<<NROWS / 128, 256, 0, stream>>>(ze, cbf, cbq, cnall, out);
}